// Round 15
// baseline (711.631 us; speedup 1.0000x reference)
//
#include <hip/hip_runtime.h>

// Problem constants (N=1)
constexpr int W_ = 160;   // input W (x)
constexpr int H_ = 192;   // input H (y)
constexpr int D_ = 64;    // input D (z)
constexpr int C_ = 32;
constexpr int HW_  = H_ * W_;          // 30720
constexpr int DHWi = D_ * HW_;         // 1966080
constexpr int CD   = C_ * D_;          // 2048

// R14: TA wall removed (global_load_lds staging, no spill) -> now VALU-bound
// (VALUBusy 75.5%). Sinks: (a) staging loop's per-LANE magic-div + addr build
// (~1000 cyc/wave); (b) boundary handling paid every k (~26 VALU/k); (c) 2.8e7
// bank conflicts (stride-32 rows are bank-aligned). R15:
//  1) SCALAR staging: rows swept with scalar (bz,by) counters; only the lane's
//     x offset is per-lane. lane<33 stages one full 33-float row (incl. x-pair
//     pad) per global_load_lds -> loop arithmetic is SALU, not VALU.
//  2) INTERIOR fast path (block-uniform): unclamped box strictly inside the
//     volume -> no clamps, no zero-checks, no x-pair shuffle. (g+1)*c folded
//     to fma(g,c,c); corner evals use the IDENTICAL tree (rigor preserved).
//  3) LDS row stride 33 (odd) -> row r bank-rotates by r; neighbor-row lanes
//     stop colliding. Reads are ds_read2_b32 pairs (offsets 0/1, 33/34).
// Keep frozen: XCD phase schedule, rigorous corner box, one barrier/block,
// R7 global-gather fallback, NT f4 stores.
constexpr int TW = 16, TH = 8, TD = 16;
constexpr int NWT = W_ / TW;             // 10
constexpr int NHT = H_ / TH;             // 24
constexpr int NDT = D_ / TD;             // 4
constexpr int QPP = NWT * NHT;           // 240 spatial blocks per (c,dt) phase
constexpr int CPX = C_ / 8;              // 4 channels per XCD
constexpr int LSTR = 33;                 // LDS row stride (floats, odd)
constexpr int RMAX = 408;                // max staged rows (BZr*BYr)
// LDS = 408*33*4 = 53856 B -> 3 blocks/CU

typedef float f4_t __attribute__((ext_vector_type(4)));
typedef float f2_t __attribute__((ext_vector_type(2)));

__global__ void __launch_bounds__(256, 4)
affine_grid_sample_kernel(const float* __restrict__ inp,
                          const float* __restrict__ th,
                          float* __restrict__ out)
{
    __shared__ float Lb[RMAX * LSTR];

    const int t   = threadIdx.x;
    const int bid = blockIdx.x;
    const int xcd = bid & 7;             // XCD id (dispatch round-robin)
    const int r_  = bid >> 3;            // within XCD, dispatch order
    const int q   = r_ % QPP;
    const int rem = r_ / QPP;            // (c_local, dt), dt fastest
    const int c   = xcd * CPX + (rem >> 2);
    const int dt  = rem & 3;
    const int hs  = q / NWT;
    const int wt  = q - hs * NWT;
    const int w0 = wt * TW, h0 = hs * TH, d0 = dt * TD;

    const float th0=th[0], th1=th[1], th2 =th[2],  th3 =th[3];
    const float th4=th[4], th5=th[5], th6 =th[6],  th7 =th[7];
    const float th8=th[8], th9=th[9], th10=th[10], th11=th[11];
    const float CX = 0.5f * (W_ - 1), CY = 0.5f * (H_ - 1), CZ = 0.5f * (D_ - 1);

    const float* __restrict__ pc = inp + (size_t)c * DHWi;

    // ---- rigorous box from 8 tile corners; IDENTICAL fp trees to the
    // per-point eval below (fma weakly monotone per argument) ----
    float pxmn= 1e30f, pxmx=-1e30f, pymn= 1e30f, pymx=-1e30f,
          pzmn= 1e30f, pzmx=-1e30f;
    #pragma unroll
    for (int ci = 0; ci < 8; ++ci) {
        const int cw = (ci & 1) ? w0 + TW - 1 : w0;
        const int chh= (ci & 2) ? h0 + TH - 1 : h0;
        const int cd = (ci & 4) ? d0 + TD - 1 : d0;
        const float zzc = fmaf((float)cd, 2.0f / (D_ - 1), -1.0f);
        const float kxc = fmaf(th2,  zzc, th3);
        const float kyc = fmaf(th6,  zzc, th7);
        const float kzc = fmaf(th10, zzc, th11);
        const float xxc = fmaf((float)cw,  2.0f / (W_ - 1), -1.0f);
        const float yyc = fmaf((float)chh, 2.0f / (H_ - 1), -1.0f);
        const float px = fmaf(fmaf(th0, xxc, fmaf(th1, yyc, kxc)), CX, CX);
        const float py = fmaf(fmaf(th4, xxc, fmaf(th5, yyc, kyc)), CY, CY);
        const float pz = fmaf(fmaf(th8, xxc, fmaf(th9, yyc, kzc)), CZ, CZ);
        pxmn = fminf(pxmn, px); pxmx = fmaxf(pxmx, px);
        pymn = fminf(pymn, py); pymx = fmaxf(pymx, py);
        pzmn = fminf(pzmn, pz); pzmx = fmaxf(pzmx, pz);
    }
    const int xlo_u = (int)floorf(pxmn), xhi_u = (int)floorf(pxmx) + 1;
    const int ylo_u = (int)floorf(pymn), yhi_u = (int)floorf(pymx) + 1;
    const int zlo_u = (int)floorf(pzmn), zhi_u = (int)floorf(pzmx) + 1;
    const int xlo = max(xlo_u, 0), xhi = min(xhi_u, W_ - 1);
    const int ylo = max(ylo_u, 0), yhi = min(yhi_u, H_ - 1);
    const int zlo = max(zlo_u, 0), zhi = min(zhi_u, D_ - 1);
    const int BXr = xhi - xlo + 1;
    const int BYr = yhi - ylo + 1;
    const int BZr = zhi - zlo + 1;
    const int R   = BZr * BYr;
    const bool fits = (BXr <= 32) && (BYr >= 4) && (R <= RMAX);
    const bool interior = (xlo_u >= 0) && (xhi_u <= W_ - 1) &&
                          (ylo_u >= 0) && (yhi_u <= H_ - 1) &&
                          (zlo_u >= 0) && (zhi_u <= D_ - 1);

    if (fits) {
        // ---- stage: one 33-float row per instruction, SCALAR loop state ----
        const int lane = t & 63;
        const int wv   = t >> 6;
        if (lane < 33) {
            // per-lane x base (clamped: pad lane may exceed W-1 harmlessly)
            const float* __restrict__ pl = pc + min(xlo + lane, W_ - 1);
            int bz = 0, by = wv;             // wv < 4 <= BYr: no initial wrap
            for (int rr = wv; rr < R; rr += 4) {
                const int go = (zlo + bz) * HW_ + (ylo + by) * W_;
                __builtin_amdgcn_global_load_lds(
                    (const __attribute__((address_space(1))) unsigned*)(pl + go),
                    (__attribute__((address_space(3))) unsigned*)&Lb[rr * LSTR],
                    4, 0, 0);
                by += 4;
                if (by >= BYr) { by -= BYr; ++bz; }   // single wrap (BYr>=4)
            }
        }
        asm volatile("s_waitcnt vmcnt(0)" ::: "memory");
    }
    __syncthreads();                         // the only barrier in the block

    // ---- per-thread outputs: (dq, wl, hl); d contiguous within thread ----
    const int dq = t & 1;
    const int wl = (t >> 1) & 15;
    const int hl = t >> 5;
    const int w  = w0 + wl;
    const int h  = h0 + hl;
    const float xx = fmaf((float)w, 2.0f / (W_ - 1), -1.0f);
    const float yy = fmaf((float)h, 2.0f / (H_ - 1), -1.0f);
    const int db = d0 + dq * 8;              // this thread's 8 contiguous d's

    f4_t val0, val1;
    const int PS = BYr * LSTR;               // plane stride (floats)

    if (fits && interior) {
        // ======== fast path: no clamps, no checks, no shuffles ========
        #pragma unroll
        for (int k = 0; k < 8; ++k) {
            const int d = db + k;
            const float zz  = fmaf((float)d, 2.0f / (D_ - 1), -1.0f);
            const float kzx = fmaf(th2,  zz, th3);
            const float kzy = fmaf(th6,  zz, th7);
            const float kzz = fmaf(th10, zz, th11);
            const float px = fmaf(fmaf(th0, xx, fmaf(th1, yy, kzx)), CX, CX);
            const float py = fmaf(fmaf(th4, xx, fmaf(th5, yy, kzy)), CY, CY);
            const float pz = fmaf(fmaf(th8, xx, fmaf(th9, yy, kzz)), CZ, CZ);
            const float fx = floorf(px), fy = floorf(py), fz = floorf(pz);
            const int ix0 = (int)fx, iy0 = (int)fy, iz0 = (int)fz;
            const float wx = px - fx, wy = py - fy, wz = pz - fz;
            const float u0 = 1.0f - wx, v0 = 1.0f - wy, s0 = 1.0f - wz;
            const int bx = ix0 - xlo;
            const int ry = iy0 - ylo;
            const int rz = iz0 - zlo;
            const int a0 = rz * PS + ry * LSTR + bx;    // taps in-box by rigor
            const int a1 = a0 + PS;
            const float a00 = Lb[a0],        b00 = Lb[a0 + 1];
            const float a01 = Lb[a0 + LSTR], b01 = Lb[a0 + LSTR + 1];
            const float a10 = Lb[a1],        b10 = Lb[a1 + 1];
            const float a11 = Lb[a1 + LSTR], b11 = Lb[a1 + LSTR + 1];
            const float x00 = u0 * a00 + wx * b00;
            const float x01 = u0 * a01 + wx * b01;
            const float x10 = u0 * a10 + wx * b10;
            const float x11 = u0 * a11 + wx * b11;
            const float e0 = v0 * x00 + wy * x01;
            const float e1 = v0 * x10 + wy * x11;
            const float v  = s0 * e0 + wz * e1;
            if (k < 4) val0[k] = v; else val1[k - 4] = v;
        }
    } else if (fits) {
        // ======== general LDS path: boundary-safe (clamps + zero weights) ====
        #pragma unroll
        for (int k = 0; k < 8; ++k) {
            const int d = db + k;
            const float zz  = fmaf((float)d, 2.0f / (D_ - 1), -1.0f);
            const float kzx = fmaf(th2,  zz, th3);
            const float kzy = fmaf(th6,  zz, th7);
            const float kzz = fmaf(th10, zz, th11);
            const float px = fmaf(fmaf(th0, xx, fmaf(th1, yy, kzx)), CX, CX);
            const float py = fmaf(fmaf(th4, xx, fmaf(th5, yy, kzy)), CY, CY);
            const float pz = fmaf(fmaf(th8, xx, fmaf(th9, yy, kzz)), CZ, CZ);
            const float fx = floorf(px), fy = floorf(py), fz = floorf(pz);
            const int ix0 = (int)fx, iy0 = (int)fy, iz0 = (int)fz;
            const float wx = px - fx, wy = py - fy, wz = pz - fz;
            // zeros-padding: per-axis weight of any OOB corner is zeroed
            const float u0r = ((unsigned)ix0       < (unsigned)W_) ? (1.0f - wx) : 0.0f;
            const float u1r = ((unsigned)(ix0 + 1) < (unsigned)W_) ? wx          : 0.0f;
            const float v0  = ((unsigned)iy0       < (unsigned)H_) ? (1.0f - wy) : 0.0f;
            const float v1  = ((unsigned)(iy0 + 1) < (unsigned)H_) ? wy          : 0.0f;
            const float s0  = ((unsigned)iz0       < (unsigned)D_) ? (1.0f - wz) : 0.0f;
            const float s1  = ((unsigned)(iz0 + 1) < (unsigned)D_) ? wz          : 0.0f;
            // x-pair on base e=clamp(ix0,0,W-2): ix0==-1 -> (u1r,0);
            // ix0==W-1 -> (0,u0r); both-OOB already zero
            float wA = u0r, wB = u1r;
            if (ix0 == -1)     { wA = u1r; wB = 0.0f; }
            if (ix0 == W_ - 1) { wA = 0.0f; wB = u0r; }
            const int e   = min(max(ix0,     0), W_ - 2);
            const int cy0 = min(max(iy0,     0), H_ - 1);
            const int cy1 = min(max(iy0 + 1, 0), H_ - 1);
            const int cz0 = min(max(iz0,     0), D_ - 1);
            const int cz1 = min(max(iz0 + 1, 0), D_ - 1);
            const int bx  = e - xlo;
            const int a00i = (cz0 - zlo) * PS + (cy0 - ylo) * LSTR + bx;
            const int a01i = (cz0 - zlo) * PS + (cy1 - ylo) * LSTR + bx;
            const int a10i = (cz1 - zlo) * PS + (cy0 - ylo) * LSTR + bx;
            const int a11i = (cz1 - zlo) * PS + (cy1 - ylo) * LSTR + bx;
            const float x00 = wA * Lb[a00i] + wB * Lb[a00i + 1];
            const float x01 = wA * Lb[a01i] + wB * Lb[a01i + 1];
            const float x10 = wA * Lb[a10i] + wB * Lb[a10i + 1];
            const float x11 = wA * Lb[a11i] + wB * Lb[a11i + 1];
            const float e0 = v0 * x00 + v1 * x01;
            const float e1 = v0 * x10 + v1 * x11;
            const float v  = s0 * e0 + s1 * e1;
            if (k < 4) val0[k] = v; else val1[k - 4] = v;
        }
    } else {
        // ======== fallback: proven R7 global x-pair gather (rare) ========
        #pragma unroll
        for (int k = 0; k < 8; ++k) {
            const int d = db + k;
            const float zz  = fmaf((float)d, 2.0f / (D_ - 1), -1.0f);
            const float kzx = fmaf(th2,  zz, th3);
            const float kzy = fmaf(th6,  zz, th7);
            const float kzz = fmaf(th10, zz, th11);
            const float px = fmaf(fmaf(th0, xx, fmaf(th1, yy, kzx)), CX, CX);
            const float py = fmaf(fmaf(th4, xx, fmaf(th5, yy, kzy)), CY, CY);
            const float pz = fmaf(fmaf(th8, xx, fmaf(th9, yy, kzz)), CZ, CZ);
            const float fx = floorf(px), fy = floorf(py), fz = floorf(pz);
            const int ix0 = (int)fx, iy0 = (int)fy, iz0 = (int)fz;
            const float wx = px - fx, wy = py - fy, wz = pz - fz;
            const float u0r = ((unsigned)ix0       < (unsigned)W_) ? (1.0f - wx) : 0.0f;
            const float u1r = ((unsigned)(ix0 + 1) < (unsigned)W_) ? wx          : 0.0f;
            const float v0  = ((unsigned)iy0       < (unsigned)H_) ? (1.0f - wy) : 0.0f;
            const float v1  = ((unsigned)(iy0 + 1) < (unsigned)H_) ? wy          : 0.0f;
            const float s0  = ((unsigned)iz0       < (unsigned)D_) ? (1.0f - wz) : 0.0f;
            const float s1  = ((unsigned)(iz0 + 1) < (unsigned)D_) ? wz          : 0.0f;
            float wA = u0r, wB = u1r;
            if (ix0 == -1)     { wA = u1r; wB = 0.0f; }
            if (ix0 == W_ - 1) { wA = 0.0f; wB = u0r; }
            const int e   = min(max(ix0,     0), W_ - 2);
            const int cy0 = min(max(iy0,     0), H_ - 1);
            const int cy1 = min(max(iy0 + 1, 0), H_ - 1);
            const int cz0 = min(max(iz0,     0), D_ - 1);
            const int cz1 = min(max(iz0 + 1, 0), D_ - 1);
            f2_t P0, P1, P2, P3;
            __builtin_memcpy(&P0, pc + (unsigned)(cz0 * HW_ + cy0 * W_ + e), 8);
            __builtin_memcpy(&P1, pc + (unsigned)(cz0 * HW_ + cy1 * W_ + e), 8);
            __builtin_memcpy(&P2, pc + (unsigned)(cz1 * HW_ + cy0 * W_ + e), 8);
            __builtin_memcpy(&P3, pc + (unsigned)(cz1 * HW_ + cy1 * W_ + e), 8);
            asm volatile("" :: "v"(P0), "v"(P1), "v"(P2), "v"(P3));
            const float x00 = wA * P0[0] + wB * P0[1];
            const float x01 = wA * P1[0] + wB * P1[1];
            const float x10 = wA * P2[0] + wB * P2[1];
            const float x11 = wA * P3[0] + wB * P3[1];
            const float e0 = v0 * x00 + v1 * x01;
            const float e1 = v0 * x10 + v1 * x11;
            const float v  = s0 * e0 + s1 * e1;
            if (k < 4) val0[k] = v; else val1[k - 4] = v;
        }
    }

    // ---- stores: 2 NT f4 per thread, 32B contiguous; lane pairs = 64B ----
    float* const ob = out + ((size_t)w * H_ + h) * CD + (size_t)c * D_ + db;
    __builtin_nontemporal_store(val0, (f4_t*)ob);
    __builtin_nontemporal_store(val1, (f4_t*)(ob + 4));
}

extern "C" void kernel_launch(void* const* d_in, const int* in_sizes, int n_in,
                              void* d_out, int out_size, void* d_ws, size_t ws_size,
                              hipStream_t stream)
{
    const float* inp = (const float*)d_in[0];   // [1,32,64,192,160] fp32
    const float* th  = (const float*)d_in[1];   // 12 fp32
    float* out = (float*)d_out;                 // [1,160,192,32,64] fp32

    // 8 XCD x (4 c x 4 dt phases) x 240 spatial = 30720 blocks
    hipLaunchKernelGGL(affine_grid_sample_kernel, dim3(8 * CPX * NDT * QPP),
                       dim3(256), 0, stream, inp, th, out);
}